// Round 3
// baseline (69.219 us; speedup 1.0000x reference)
//
#include <hip/hip_runtime.h>

#ifndef __has_builtin
#define __has_builtin(x) 0
#endif

__device__ __forceinline__ float fexp2(float x) {
#if __has_builtin(__builtin_amdgcn_exp2f)
    return __builtin_amdgcn_exp2f(x);   // v_exp_f32: 2^x
#else
    return exp2f(x);
#endif
}

__device__ __forceinline__ float fcos_rev(float r) {
#if __has_builtin(__builtin_amdgcn_cosf)
    return __builtin_amdgcn_cosf(r);    // v_cos_f32: cos(2*pi*r), r in revolutions
#else
    return __cosf(r * 6.283185307179586f);
#endif
}

constexpr int NATOMS = 512;
constexpr int NP     = 16;

// eta=16, delta=0.26875, shifts s_p = 0.9 + p*delta, anchors s_4=1.975, s_12=4.125
// Gaussian ladder in base-2 domain (see R1):
//   g_p = 2^(C t_p^2), C = -16*log2(e); g_{p+1} = g_p * w, w stepped by k2 = 2^(-A*delta)
//   A = 32*delta*log2(e), B = -16*delta^2*log2(e)
// Lower anchor never underflows for d in (0,5.2); upper anchor underflow only when
// all upper-half Gaussians < 1e-15. Verified passing (absmax 0.5 vs thr 2.52).

__device__ __forceinline__ void process_elem(float dv, float zv, float* acc,
                                             float k2, float cwh, float cvh) {
    const float C   = -23.083120654223414f;
    const float A   = 12.407177351645085f;
    const float B   = -1.6672144566f;
    const float REV = 0.09615384615384616f;   // 1/(2*5.2), cos arg in revolutions

    // All compacted elements satisfy 0 < d < 5.2 — no mask needed here.
    float fc = fmaf(0.5f, fcos_rev(dv * REV), 0.5f);
    float we = zv * fc;

    float tl = dv - 1.975f;                   // t_4
    float th = dv - 4.125f;                   // t_12
    float gl = we * fexp2((C * tl) * tl);     // g_4 * we
    float gh = we * fexp2((C * th) * th);     // g_12 * we
    float wl = fexp2(fmaf(A, tl, B));         // w_4
    float vl = fexp2(fmaf(-A, tl, B));        // v_4
    float wh = wl * cwh;                      // w_12
    float vh = vl * cvh;                      // v_12

    acc[4] += gl;
    float g = gl * wl; acc[5] += g; wl *= k2;
    g = g * wl;        acc[6] += g; wl *= k2;
    g = g * wl;        acc[7] += g;
    g = gl * vl;       acc[3] += g; vl *= k2;
    g = g * vl;        acc[2] += g; vl *= k2;
    g = g * vl;        acc[1] += g; vl *= k2;
    g = g * vl;        acc[0] += g;

    acc[12] += gh;
    g = gh * wh;       acc[13] += g; wh *= k2;
    g = g * wh;        acc[14] += g; wh *= k2;
    g = g * wh;        acc[15] += g;
    g = gh * vh;       acc[11] += g; vh *= k2;
    g = g * vh;        acc[10] += g; vh *= k2;
    g = g * vh;        acc[9]  += g; vh *= k2;
    g = g * vh;        acc[8]  += g;
}

__global__ __launch_bounds__(256, 4) void aev_radial_kernel(
        const float* __restrict__ d,   // (B, N, N)
        const float* __restrict__ z,   // (B, N)
        float* __restrict__ out)       // (B, N, NP)
{
    const int lane = threadIdx.x & 63;
    const int wave = threadIdx.x >> 6;
    const int row  = blockIdx.x * 4 + wave;      // row = b*N + i, in [0, 8192)
    const int b    = row >> 9;                   // N = 512

    const float4* __restrict__ dd = reinterpret_cast<const float4*>(d + (size_t)row * NATOMS);
    const float4* __restrict__ zz = reinterpret_cast<const float4*>(z + (size_t)b   * NATOMS);

    // Per-wave compaction buffer: (d, z) pairs of valid elements.
    // Max valid per row = 511 (diagonal always invalid) <= 512 slots.
    __shared__ float2 buf[4][NATOMS];
    float2* __restrict__ wbuf = buf[wave];

    const float k2  = fexp2(-3.3344289132f);    // 2^(-A*delta)
    const float cwh = fexp2(-26.675431306f);    // 2^(-A*2.15)
    const float cvh = fexp2( 26.675431306f);    // 2^(+A*2.15)

    // ---- Phase 1: stream row, ballot-compact valid (0 < d < 5.2) pairs into LDS ----
    unsigned int cnt = 0;
#pragma unroll
    for (int h = 0; h < 2; ++h) {
        float4 dv4 = dd[lane + 64 * h];
        float4 zv4 = zz[lane + 64 * h];
#pragma unroll
        for (int q = 0; q < 4; ++q) {
            float dv = (&dv4.x)[q];
            float zv = (&zv4.x)[q];
            bool valid = (dv < 5.2f) && (dv != 0.0f);
            unsigned long long bal = __ballot(valid);
            unsigned int lo = (unsigned int)(bal & 0xffffffffull);
            unsigned int hi = (unsigned int)(bal >> 32);
            unsigned int prefix = __builtin_amdgcn_mbcnt_hi(hi,
                                    __builtin_amdgcn_mbcnt_lo(lo, 0));
            if (valid) {
                wbuf[cnt + prefix] = make_float2(dv, zv);
            }
            cnt += (unsigned int)__popcll(bal);   // uniform: s_bcnt1 + s_add
        }
    }

    // ---- Phase 2: process only the compacted elements ----
    float acc[NP];
#pragma unroll
    for (int p = 0; p < NP; ++p) acc[p] = 0.0f;

    const unsigned int rounds = (cnt + 63u) >> 6;   // wave-uniform trip count
    for (unsigned int r = 0; r < rounds; ++r) {
        unsigned int idx = (r << 6) + lane;
        float2 e = wbuf[idx];                 // tail lanes read garbage; selected away
        bool ok  = idx < cnt;
        float dv = ok ? e.x : 3.0f;           // benign sentinel
        float zv = ok ? e.y : 0.0f;           // zero weight -> zero contribution
        process_elem(dv, zv, acc, k2, cwh, cvh);
    }

    // ---- Lane-halving butterfly reduction (16 accs x 64 lanes -> 16 outputs) ----
    bool u;
    float r0[8];
    u = (lane & 1) != 0;
#pragma unroll
    for (int k = 0; k < 8; ++k) {
        float snd  = u ? acc[k] : acc[k + 8];
        float rcv  = __shfl_xor(snd, 1, 64);
        float kept = u ? acc[k + 8] : acc[k];
        r0[k] = kept + rcv;
    }
    float r1[4];
    u = (lane & 2) != 0;
#pragma unroll
    for (int k = 0; k < 4; ++k) {
        float snd  = u ? r0[k] : r0[k + 4];
        float rcv  = __shfl_xor(snd, 2, 64);
        float kept = u ? r0[k + 4] : r0[k];
        r1[k] = kept + rcv;
    }
    float r2[2];
    u = (lane & 4) != 0;
#pragma unroll
    for (int k = 0; k < 2; ++k) {
        float snd  = u ? r1[k] : r1[k + 2];
        float rcv  = __shfl_xor(snd, 4, 64);
        float kept = u ? r1[k + 2] : r1[k];
        r2[k] = kept + rcv;
    }
    float r3;
    u = (lane & 8) != 0;
    {
        float snd  = u ? r2[0] : r2[1];
        float rcv  = __shfl_xor(snd, 8, 64);
        float kept = u ? r2[1] : r2[0];
        r3 = kept + rcv;
    }
    r3 += __shfl_xor(r3, 16, 64);
    r3 += __shfl_xor(r3, 32, 64);

    // acc index held by this lane: bit-reversal of (lane & 15)
    int idx = ((lane & 1) << 3) | ((lane & 2) << 1) | ((lane & 4) >> 1) | ((lane & 8) >> 3);
    if (lane < 16) {
        out[(size_t)row * NP + idx] = r3;
    }
}

extern "C" void kernel_launch(void* const* d_in, const int* in_sizes, int n_in,
                              void* d_out, int out_size, void* d_ws, size_t ws_size,
                              hipStream_t stream) {
    const float* d  = (const float*)d_in[0];   // (16, 512, 512) fp32
    const float* z  = (const float*)d_in[1];   // (16, 512) fp32
    float* out      = (float*)d_out;           // (16, 512, 16) fp32

    aev_radial_kernel<<<dim3(2048), dim3(256), 0, stream>>>(d, z, out);
}

// Round 4
// 67.394 us; speedup vs baseline: 1.0271x; 1.0271x over previous
//
#include <hip/hip_runtime.h>

#ifndef __has_builtin
#define __has_builtin(x) 0
#endif

__device__ __forceinline__ float fexp2(float x) {
#if __has_builtin(__builtin_amdgcn_exp2f)
    return __builtin_amdgcn_exp2f(x);   // v_exp_f32: 2^x
#else
    return exp2f(x);
#endif
}

__device__ __forceinline__ float fcos_rev(float r) {
#if __has_builtin(__builtin_amdgcn_cosf)
    return __builtin_amdgcn_cosf(r);    // v_cos_f32: cos(2*pi*r), r in revolutions
#else
    return __cosf(r * 6.283185307179586f);
#endif
}

typedef __attribute__((ext_vector_type(2))) float v2f;

// Packed FP32 (VOP3P, FeaturePackedFP32Ops — gfx90a+, present on gfx950).
// Two independent j-elements ride in one 64-bit VGPR pair; halves ladder instrs.
__device__ __forceinline__ v2f pk_mul(v2f a, v2f b) {
    v2f d;
    asm("v_pk_mul_f32 %0, %1, %2" : "=v"(d) : "v"(a), "v"(b));
    return d;
}
__device__ __forceinline__ v2f pk_add(v2f a, v2f b) {
    v2f d;
    asm("v_pk_add_f32 %0, %1, %2" : "=v"(d) : "v"(a), "v"(b));
    return d;
}

constexpr int NATOMS = 512;
constexpr int NP     = 16;

// eta=16, delta=0.26875, shifts s_p = 0.9 + p*delta, anchors s_4=1.975, s_12=4.125
// Gaussian ladder in base-2 domain (verified R1/R2, absmax 0.5 vs thr 2.52):
//   g_p = 2^(C t_p^2), C = -16*log2(e)
//   g_{p+1} = g_p * w,  w = 2^(A t + B) stepped by k2 = 2^(-A*delta)
//   g_{p-1} = g_p * v,  v = 2^(-A t + B) stepped by k2
//   A = 32*delta*log2(e) = 12.407177351645085, B = -16*delta^2*log2(e)
// Upper-anchor (p=12) factors: w_h = w_l * 2^(-A*2.15), v_h = v_l * 2^(+A*2.15)

// Scalar per-element setup: mask, cutoff cosine, anchor Gaussians, ladder factors.
__device__ __forceinline__ void setup_elem(float dv, float zv,
                                           float& gl, float& gh,
                                           float& wl, float& vl) {
    const float C   = -23.083120654223414f;
    const float A   = 12.407177351645085f;
    const float B   = -1.6672144566f;
    const float REV = 0.09615384615384616f;   // 1/(2*5.2), cos arg in revolutions

    bool  valid = (dv < 5.2f) && (dv != 0.0f);
    float fc    = fmaf(0.5f, fcos_rev(dv * REV), 0.5f);
    float we    = valid ? zv * fc : 0.0f;

    float tl = dv - 1.975f;                   // t_4
    float th = dv - 4.125f;                   // t_12
    gl = we * fexp2((C * tl) * tl);           // g_4 * we
    gh = we * fexp2((C * th) * th);           // g_12 * we
    wl = fexp2(fmaf(A, tl, B));               // w_4
    vl = fexp2(fmaf(-A, tl, B));              // v_4
}

// Packed ladder: processes a PAIR of elements per instruction.
__device__ __forceinline__ void ladder_pair(v2f* acc2, v2f GL, v2f GH,
                                            v2f WL, v2f VL,
                                            v2f K2, v2f CWH, v2f CVH) {
    v2f g, w, v;
    // lower half, anchor p=4
    acc2[4] = pk_add(acc2[4], GL);
    g = pk_mul(GL, WL); acc2[5] = pk_add(acc2[5], g); w = pk_mul(WL, K2);
    g = pk_mul(g,  w ); acc2[6] = pk_add(acc2[6], g); w = pk_mul(w,  K2);
    g = pk_mul(g,  w ); acc2[7] = pk_add(acc2[7], g);
    g = pk_mul(GL, VL); acc2[3] = pk_add(acc2[3], g); v = pk_mul(VL, K2);
    g = pk_mul(g,  v ); acc2[2] = pk_add(acc2[2], g); v = pk_mul(v,  K2);
    g = pk_mul(g,  v ); acc2[1] = pk_add(acc2[1], g); v = pk_mul(v,  K2);
    g = pk_mul(g,  v ); acc2[0] = pk_add(acc2[0], g);
    // upper half, anchor p=12
    v2f WH = pk_mul(WL, CWH);
    v2f VH = pk_mul(VL, CVH);
    acc2[12] = pk_add(acc2[12], GH);
    g = pk_mul(GH, WH); acc2[13] = pk_add(acc2[13], g); w = pk_mul(WH, K2);
    g = pk_mul(g,  w ); acc2[14] = pk_add(acc2[14], g); w = pk_mul(w,  K2);
    g = pk_mul(g,  w ); acc2[15] = pk_add(acc2[15], g);
    g = pk_mul(GH, VH); acc2[11] = pk_add(acc2[11], g); v = pk_mul(VH, K2);
    g = pk_mul(g,  v ); acc2[10] = pk_add(acc2[10], g); v = pk_mul(v,  K2);
    g = pk_mul(g,  v ); acc2[9]  = pk_add(acc2[9],  g); v = pk_mul(v,  K2);
    g = pk_mul(g,  v ); acc2[8]  = pk_add(acc2[8],  g);
}

__global__ __launch_bounds__(256, 4) void aev_radial_kernel(
        const float* __restrict__ d,   // (B, N, N)
        const float* __restrict__ z,   // (B, N)
        float* __restrict__ out)       // (B, N, NP)
{
    const int lane = threadIdx.x & 63;
    const int wave = threadIdx.x >> 6;
    const int row  = blockIdx.x * 4 + wave;      // row = b*N + i, in [0, 8192)
    const int b    = row >> 9;                   // N = 512

    const float4* __restrict__ dd = reinterpret_cast<const float4*>(d + (size_t)row * NATOMS);
    const float4* __restrict__ zz = reinterpret_cast<const float4*>(z + (size_t)b   * NATOMS);

    const float k2v  = fexp2(-3.3344289132f);    // 2^(-A*delta)
    const float cwhv = fexp2(-26.675431306f);    // 2^(-A*2.15)
    const float cvhv = fexp2( 26.675431306f);    // 2^(+A*2.15)
    const v2f K2  = {k2v,  k2v};
    const v2f CWH = {cwhv, cwhv};
    const v2f CVH = {cvhv, cvhv};

    v2f acc2[NP];
#pragma unroll
    for (int p = 0; p < NP; ++p) acc2[p] = (v2f){0.0f, 0.0f};

#pragma unroll
    for (int h = 0; h < 2; ++h) {
        float4 dv4 = dd[lane + 64 * h];
        float4 zv4 = zz[lane + 64 * h];
#pragma unroll
        for (int pr = 0; pr < 2; ++pr) {         // two pairs per float4
            float d0 = (&dv4.x)[2 * pr],     z0 = (&zv4.x)[2 * pr];
            float d1 = (&dv4.x)[2 * pr + 1], z1 = (&zv4.x)[2 * pr + 1];
            float gl0, gh0, wl0, vl0, gl1, gh1, wl1, vl1;
            setup_elem(d0, z0, gl0, gh0, wl0, vl0);
            setup_elem(d1, z1, gl1, gh1, wl1, vl1);
            v2f GL = {gl0, gl1}, GH = {gh0, gh1};
            v2f WL = {wl0, wl1}, VL = {vl0, vl1};
            ladder_pair(acc2, GL, GH, WL, VL, K2, CWH, CVH);
        }
    }

    // Collapse packed halves (independent partial sums over j) to scalar.
    float acc[NP];
#pragma unroll
    for (int p = 0; p < NP; ++p) acc[p] = acc2[p].x + acc2[p].y;

    // Lane-halving butterfly reduction (16 accs x 64 lanes -> 16 outputs)
    bool u;
    float r0[8];
    u = (lane & 1) != 0;
#pragma unroll
    for (int k = 0; k < 8; ++k) {
        float snd  = u ? acc[k] : acc[k + 8];
        float rcv  = __shfl_xor(snd, 1, 64);
        float kept = u ? acc[k + 8] : acc[k];
        r0[k] = kept + rcv;
    }
    float r1[4];
    u = (lane & 2) != 0;
#pragma unroll
    for (int k = 0; k < 4; ++k) {
        float snd  = u ? r0[k] : r0[k + 4];
        float rcv  = __shfl_xor(snd, 2, 64);
        float kept = u ? r0[k + 4] : r0[k];
        r1[k] = kept + rcv;
    }
    float r2[2];
    u = (lane & 4) != 0;
#pragma unroll
    for (int k = 0; k < 2; ++k) {
        float snd  = u ? r1[k] : r1[k + 2];
        float rcv  = __shfl_xor(snd, 4, 64);
        float kept = u ? r1[k + 2] : r1[k];
        r2[k] = kept + rcv;
    }
    float r3;
    u = (lane & 8) != 0;
    {
        float snd  = u ? r2[0] : r2[1];
        float rcv  = __shfl_xor(snd, 8, 64);
        float kept = u ? r2[1] : r2[0];
        r3 = kept + rcv;
    }
    r3 += __shfl_xor(r3, 16, 64);
    r3 += __shfl_xor(r3, 32, 64);

    // acc index held by this lane: bit-reversal of (lane & 15)
    int idx = ((lane & 1) << 3) | ((lane & 2) << 1) | ((lane & 4) >> 1) | ((lane & 8) >> 3);
    if (lane < 16) {
        out[(size_t)row * NP + idx] = r3;
    }
}

extern "C" void kernel_launch(void* const* d_in, const int* in_sizes, int n_in,
                              void* d_out, int out_size, void* d_ws, size_t ws_size,
                              hipStream_t stream) {
    const float* d  = (const float*)d_in[0];   // (16, 512, 512) fp32
    const float* z  = (const float*)d_in[1];   // (16, 512) fp32
    float* out      = (float*)d_out;           // (16, 512, 16) fp32

    aev_radial_kernel<<<dim3(2048), dim3(256), 0, stream>>>(d, z, out);
}